// Round 1
// 245.788 us; speedup vs baseline: 1.0113x; 1.0113x over previous
//
#include <hip/hip_runtime.h>

#define DCH 512     // channels
#define RPB 16      // rows per block
#define NW  (RPB + 6)   // window rows: r0-3 .. r0+RPB+2

typedef float f32x4 __attribute__((ext_vector_type(4)));

__global__ __launch_bounds__(128) void ppeg_dwconv_kernel(
    const float* __restrict__ x,
    const float* __restrict__ w3, const float* __restrict__ b3,
    const float* __restrict__ w5, const float* __restrict__ b5,
    const float* __restrict__ w7, const float* __restrict__ b7,
    const int* __restrict__ lengths,
    float* __restrict__ out, int n_rows, int n_bags, int nblocks)
{
    __shared__ int soff[40];   // prefix offsets, n_bags+1 entries

    const int tid = threadIdx.x;
    const int c0  = tid * 4;           // this thread's 4 channels

    // XCD-aware bijective swizzle (8 XCDs): consecutive tiles -> same XCD so
    // 6-row halos between neighboring tiles hit that XCD's L2.
    int bid = blockIdx.x;
    {
        const int nx = 8;
        const int q  = nblocks / nx, rm = nblocks % nx;
        const int xcd = bid % nx, idx = bid / nx;
        bid = (xcd < rm ? xcd * (q + 1) : rm * (q + 1) + (xcd - rm) * q) + idx;
    }
    const int r0 = bid * RPB;
    if (r0 >= n_rows) return;

    // ---- Issue ALL 22 window-row loads up front: 22 independent float4
    // loads in flight per wave (MLP ~22 KB/wave vs 1 KB before). ----
    float4 win[NW];
    if (r0 >= 3 && r0 + RPB + 2 < n_rows) {
        const float* xp = x + (size_t)(r0 - 3) * DCH + c0;
        #pragma unroll
        for (int j = 0; j < NW; ++j)
            win[j] = *(const float4*)(xp + (size_t)j * DCH);
    } else {
        #pragma unroll
        for (int j = 0; j < NW; ++j) {
            const int rr = r0 - 3 + j;
            win[j] = (rr >= 0 && rr < n_rows)
                       ? *(const float4*)(x + (size_t)rr * DCH + c0)
                       : make_float4(0.f, 0.f, 0.f, 0.f);
        }
    }

    // ---- Prefix offsets (thread 0) — overlaps with the loads above. ----
    if (tid == 0) {
        int acc = 0;
        for (int i = 0; i < n_bags; ++i) { soff[i] = acc; acc += lengths[i]; }
        soff[n_bags] = acc;
    }

    // ---- Fold the three depthwise kernels + residual into one 7-tap. ----
    float W[7][4], bias[4];
    #pragma unroll
    for (int q2 = 0; q2 < 4; ++q2) {
        const int d = c0 + q2;
        const float a0 = w7[d*7+0], a1 = w7[d*7+1], a2 = w7[d*7+2], a3 = w7[d*7+3],
                    a4 = w7[d*7+4], a5 = w7[d*7+5], a6 = w7[d*7+6];
        const float f0 = w5[d*5+0], f1 = w5[d*5+1], f2 = w5[d*5+2], f3 = w5[d*5+3], f4 = w5[d*5+4];
        const float e0 = w3[d*3+0], e1 = w3[d*3+1], e2 = w3[d*3+2];
        W[0][q2] = a0;
        W[1][q2] = a1 + f0;
        W[2][q2] = a2 + f1 + e0;
        W[3][q2] = a3 + f2 + e1 + 1.0f;
        W[4][q2] = a4 + f3 + e2;
        W[5][q2] = a5 + f4;
        W[6][q2] = a6;
        bias[q2] = b3[d] + b5[d] + b7[d];
    }

    __syncthreads();

    // ---- Binary search for bag containing r0 (uniform, 5 LDS reads). ----
    int b = 0;
    #pragma unroll
    for (int s = 16; s >= 1; s >>= 1)
        if (b + s < n_bags && soff[b + s] <= r0) b += s;

    // A 16-row tile crosses at most one bag boundary (min bag = 2049 rows),
    // so hoist the two candidate bags' boundaries into registers:
    // per-row loop then touches NO LDS.
    const int e0b = soff[b];
    const int e1b = soff[b + 1];
    const int e2b = (b + 2 <= n_bags) ? soff[b + 2] : e1b;

    #pragma unroll
    for (int i = 0; i < RPB; ++i) {
        const int r = r0 + i;
        if (r < n_rows) {
            const bool nb   = (r >= e1b);          // row fell into next bag
            const int  offb = nb ? e1b : e0b;
            const int  endb = nb ? e2b : e1b;
            const int  t    = r - offb - 1;        // body position; -1 => cls
            const int  Lb1  = endb - offb - 1;     // body length

            float4 o;
            if (t < 0) {
                o = win[i + 3];                    // cls row: pass-through
            } else if (t >= 3 && t + 3 < Lb1) {
                // Interior fast path: pure FMA chain, no masks.
                float a0 = bias[0], a1 = bias[1], a2 = bias[2], a3 = bias[3];
                #pragma unroll
                for (int dt = 0; dt < 7; ++dt) {
                    const float4 v = win[i + dt];
                    a0 = fmaf(W[dt][0], v.x, a0);
                    a1 = fmaf(W[dt][1], v.y, a1);
                    a2 = fmaf(W[dt][2], v.z, a2);
                    a3 = fmaf(W[dt][3], v.w, a3);
                }
                o = make_float4(a0, a1, a2, a3);
            } else {
                // Bag-edge path (rare): masked taps reproduce zero padding.
                float a0 = bias[0], a1 = bias[1], a2 = bias[2], a3 = bias[3];
                #pragma unroll
                for (int dt = 0; dt < 7; ++dt) {
                    const int  tp    = t + dt - 3;
                    const bool valid = (tp >= 0) && (tp < Lb1);
                    const float mm   = valid ? 1.0f : 0.0f;
                    const float4 v = win[i + dt];
                    a0 = fmaf(mm * W[dt][0], v.x, a0);
                    a1 = fmaf(mm * W[dt][1], v.y, a1);
                    a2 = fmaf(mm * W[dt][2], v.z, a2);
                    a3 = fmaf(mm * W[dt][3], v.w, a3);
                }
                o = make_float4(a0, a1, a2, a3);
            }

            // Output is write-once: nontemporal keeps L2 for input halos.
            f32x4 ov = {o.x, o.y, o.z, o.w};
            __builtin_nontemporal_store(ov, (f32x4*)(out + (size_t)r * DCH + c0));
        }
    }
}

extern "C" void kernel_launch(void* const* d_in, const int* in_sizes, int n_in,
                              void* d_out, int out_size, void* d_ws, size_t ws_size,
                              hipStream_t stream) {
    const float* x       = (const float*)d_in[0];
    const float* w3      = (const float*)d_in[1];
    const float* b3      = (const float*)d_in[2];
    const float* w5      = (const float*)d_in[3];
    const float* b5      = (const float*)d_in[4];
    const float* w7      = (const float*)d_in[5];
    const float* b7      = (const float*)d_in[6];
    const int*   lengths = (const int*)d_in[7];

    const int n_bags = in_sizes[7];
    const int n_rows = in_sizes[0] / DCH;
    float* out = (float*)d_out;

    const int nblocks = (n_rows + RPB - 1) / RPB;
    ppeg_dwconv_kernel<<<nblocks, 128, 0, stream>>>(
        x, w3, b3, w5, b5, w7, b7, lengths, out, n_rows, n_bags, nblocks);
}